// Round 3
// baseline (1291.581 us; speedup 1.0000x reference)
//
#include <hip/hip_runtime.h>
#include <cstdint>
#include <cstddef>

// ---------------- problem constants ----------------
constexpr int Bn = 24;
constexpr int Dd = 128;
constexpr int Nn = 2048;
constexpr int DN = Dd * Nn;        // 262144 elements per (b, slot)
constexpr float INV_KEEP = 1.0f / 0.9f;

// ---------------- vector types ----------------
typedef __attribute__((ext_vector_type(8))) short short8;     // 8 bf16 in 4 VGPRs
typedef __attribute__((ext_vector_type(16))) float floatx16;  // MFMA 32x32 acc

union U8 { uint32_t u[4]; short8 v; uint4 q; };
union F4 { float4 v; float f[4]; };

__device__ __forceinline__ uint32_t f2bf(float f) {
  uint32_t u = __builtin_bit_cast(uint32_t, f);
  return (u + 0x7fffu + ((u >> 16) & 1u)) >> 16;   // RNE
}
__device__ __forceinline__ float bf2f(uint32_t h) {
  return __builtin_bit_cast(float, h << 16);
}

__device__ __forceinline__ floatx16 MFMA(short8 a, short8 b, floatx16 c) {
  return __builtin_amdgcn_mfma_f32_32x32x16_bf16(a, b, c, 0, 0, 0);
}

// ---------------- threefry2x32, key = jax.random.key(42) => (0, 42) ----------------
__device__ __forceinline__ uint32_t rotl32(uint32_t x, int r) {
  return (x << r) | (x >> (32 - r));
}
__device__ __forceinline__ void tf2x32(uint32_t& x0, uint32_t& x1) {
  const uint32_t k0 = 0u, k1 = 42u, k2 = 0x1BD11BDAu ^ 0u ^ 42u;
  x0 += k0; x1 += k1;
#define TFR(r) { x0 += x1; x1 = rotl32(x1, (r)); x1 ^= x0; }
  TFR(13) TFR(15) TFR(26) TFR(6)   x0 += k1; x1 += k2 + 1u;
  TFR(17) TFR(29) TFR(16) TFR(24)  x0 += k2; x1 += k0 + 2u;
  TFR(13) TFR(15) TFR(26) TFR(6)   x0 += k0; x1 += k1 + 3u;
  TFR(17) TFR(29) TFR(16) TFR(24)  x0 += k1; x1 += k2 + 4u;
  TFR(13) TFR(15) TFR(26) TFR(6)   x0 += k2; x1 += k0 + 5u;
#undef TFR
}
__device__ __forceinline__ bool keep_flag(uint32_t j) {
  uint32_t x0 = 0u, x1 = j;       // partitionable threefry (verified passing R2-R4)
  tf2x32(x0, x1);
  return ((x0 ^ x1) >> 9) < 7549747u;
}

// ---------------- P0: sc[b,n] = sum_d Wc[b,d] C[b,d,n]; sq = Wq . Q ----------------
__global__ void scq_kernel(const float* __restrict__ Cp, const float* __restrict__ Qp,
                           const float* __restrict__ Wp,
                           float* __restrict__ sc, float* __restrict__ sq) {
  const int z = blockIdx.z;
  const int b = blockIdx.y;
  const int n = blockIdx.x * 256 + threadIdx.x;
  const float* X = z ? Qp : Cp;
  const float* Wb = Wp + b * 384 + (z ? 0 : 128);
  const float* Xb = X + (size_t)b * DN + n;
  float acc = 0.f;
#pragma unroll 8
  for (int d = 0; d < Dd; ++d) acc = fmaf(Wb[d], Xb[(size_t)d * Nn], acc);
  (z ? sq : sc)[b * Nn + n] = acc;
}

// ---------------- bias adjust: v[b,:] -= max(v[b,:]) (fixed-bound softmax shift) --
__global__ __launch_bounds__(256) void bias_adjust_kernel(float* __restrict__ sc,
                                                          float* __restrict__ sq) {
  __shared__ float red[256];
  const int tid = threadIdx.x;
  float* v = ((blockIdx.x & 1) ? sq : sc) + (size_t)(blockIdx.x >> 1) * Nn;
  float m = -__builtin_inff();
#pragma unroll
  for (int i = 0; i < 8; ++i) m = fmaxf(m, v[tid + 256 * i]);
  red[tid] = m;
  __syncthreads();
  for (int s = 128; s > 0; s >>= 1) {
    if (tid < s) red[tid] = fmaxf(red[tid], red[tid + s]);
    __syncthreads();
  }
  const float mm = red[0];
#pragma unroll
  for (int i = 0; i < 8; ++i) v[tid + 256 * i] -= mm;
}

// ---------------- cvt: C,Q fp32 [d][n] -> bf16 [d][n] into slot0 (lo=C, hi=Q) ----
__global__ __launch_bounds__(256) void cvt_kernel(const float* __restrict__ Cp,
                                                  const float* __restrict__ Qp,
                                                  float* __restrict__ outp) {
  const size_t i = ((size_t)blockIdx.x * 256 + threadIdx.x) * 8;   // over Bn*DN
  const int b = (int)(i >> 18);
  const int rem = (int)(i & (DN - 1));
  uint16_t* d0 = (uint16_t*)(outp + (size_t)b * 4 * DN);
  {
    const float4 a = *(const float4*)(Cp + i);
    const float4 c = *(const float4*)(Cp + i + 4);
    U8 t;
    t.u[0] = f2bf(a.x) | (f2bf(a.y) << 16);
    t.u[1] = f2bf(a.z) | (f2bf(a.w) << 16);
    t.u[2] = f2bf(c.x) | (f2bf(c.y) << 16);
    t.u[3] = f2bf(c.z) | (f2bf(c.w) << 16);
    *(uint4*)(d0 + rem) = t.q;
  }
  {
    const float4 a = *(const float4*)(Qp + i);
    const float4 c = *(const float4*)(Qp + i + 4);
    U8 t;
    t.u[0] = f2bf(a.x) | (f2bf(a.y) << 16);
    t.u[1] = f2bf(a.z) | (f2bf(a.w) << 16);
    t.u[2] = f2bf(c.x) | (f2bf(c.y) << 16);
    t.u[3] = f2bf(c.z) | (f2bf(c.w) << 16);
    *(uint4*)(d0 + DN + rem) = t.q;
  }
}

// ---------------- split+transpose: X[b][d][n] fp32 -> hi/lo bf16 [b][n][d] -------
// Q -> slot1 ; C -> slot3. (hi first DN ushorts, lo next DN)
__global__ __launch_bounds__(256) void split_kernel(const float* __restrict__ Cp,
                                                    const float* __restrict__ Qp,
                                                    float* __restrict__ outp) {
  __shared__ float T[64 * 129];
  const int tid = threadIdx.x;
  const int nt = blockIdx.x, src = blockIdx.y, b = blockIdx.z;
  const float* X = (src ? Qp : Cp) + (size_t)b * DN;
  float* outb = outp + (size_t)b * 4 * DN;
  uint16_t* dsth = (uint16_t*)(outb + (size_t)(src ? 1 : 3) * DN);
  uint16_t* dstl = dsth + DN;
  const int n = nt * 64 + (tid & 63);
  const int dg0 = (tid >> 6) * 32;
#pragma unroll
  for (int r = 0; r < 32; ++r)
    T[(tid & 63) * 129 + dg0 + r] = X[(size_t)(dg0 + r) * Nn + n];
  __syncthreads();
#pragma unroll
  for (int r = 0; r < 4; ++r) {
    const int item = tid + 256 * r;
    const int row = item >> 4;
    const int ch = item & 15;
    const float* tp = T + row * 129 + ch * 8;
    U8 H, L;
#pragma unroll
    for (int e = 0; e < 4; ++e) {
      const float va = tp[2 * e], vb = tp[2 * e + 1];
      const uint32_t ha = f2bf(va), hb = f2bf(vb);
      H.u[e] = ha | (hb << 16);
      L.u[e] = f2bf(va - bf2f(ha)) | (f2bf(vb - bf2f(hb)) << 16);
    }
    const size_t o = (size_t)(nt * 64 + row) * 128 + ch * 8;
    *(uint4*)(dsth + o) = H.q;
    *(uint4*)(dstl + o) = L.q;
  }
}

// ---------------- barrier-free flash pass: 1-wave blocks, fixed-bound softmax ----
// mode 0 (U2 pass): x=m, stream n. B=C^T (slot3), V=C bf16 (slot0-lo),
//                   bias=sc'. out U2 bf16 -> slot2-lo.
// mode 1 (A):       x=n, stream m. B=Q^T (slot1), V=Q bf16 (slot0-hi),
//                   bias=sq'. out A fp32 -> slot3.
// mode 2 (Bt):      x=n, stream m. B=Q^T (slot1), V=U2 bf16 (slot2-lo),
//                   bias=sq'. out Bt fp32 -> slot0-lo(d<64)/slot2-hi(d>=64).
// Softmax uses a FIXED per-x shift (3*||u_x|| + per-b max(bias), pre-subtracted):
// shift-invariant => identical result; removes all online-softmax state.
// P stays in-register: permuted-k mapping (k-lo <-> y{0-3,8-11}, k-hi <->
// y{4-7,12-15}, mirrored in V addressing) makes the MFMA S-output registers
// pack DIRECTLY into PV B-fragments. Zero LDS, zero barriers, zero shuffles
// in the loop. Grid is XCD-mapped: bid&7 = XCD; A/Bt blocks of same (b,x0)
// adjacent on the same XCD (shared B-stream in L2).
__global__ __launch_bounds__(64, 2) void flash_kernel(
    const float* __restrict__ Cp, const float* __restrict__ Qp,
    const float* __restrict__ Wp, float* __restrict__ outp,
    const float* __restrict__ scp, const float* __restrict__ sqp,
    const int fused) {
  const int tid = threadIdx.x;
  const int l31 = tid & 31, lh = tid >> 5;

  const int bid = blockIdx.x;
  const int g = bid & 7;                 // XCD (HW round-robins wg -> XCD by id)
  const int j = bid >> 3;
  int mode, b, xt;
  if (fused) {                           // 3072 = 8 XCD x 3 b x (2 modes x 64 xt)
    b = g * 3 + (j >> 7);
    const int jj = j & 127;
    mode = 1 + (jj & 1);
    xt = jj >> 1;
  } else {                               // 1536 = 8 XCD x 3 b x 64 xt
    b = g * 3 + (j >> 6);
    mode = 0;
    xt = j & 63;
  }
  const int x0 = xt * 32;

  float* outb = outp + (size_t)b * 4 * DN;
  const float* Wmb = Wp + b * 384 + 256;
  const float* Asrc = (mode == 0 ? Qp : Cp) + (size_t)b * DN;   // x-side fp32
  const uint16_t* BTh = (const uint16_t*)(outb + (size_t)(mode == 0 ? 3 : 1) * DN);
  const uint16_t* BTl = BTh + DN;
  const uint16_t* Vb = (mode == 0) ? (const uint16_t*)outb
                     : (mode == 1) ? (const uint16_t*)outb + DN
                                   : (const uint16_t*)(outb + 2 * DN);
  const float* byp = ((mode == 0) ? scp : sqp) + (size_t)b * Nn;

  // ---- x-side fragments (wm * Asrc), hi/lo split + exact sigma_x ----
  short8 xfh[8], xfl[8];
  float sig2 = 0.f;
  {
    const int xg = x0 + l31;
#pragma unroll
    for (int ks = 0; ks < 8; ++ks) {
      U8 th, tl;
#pragma unroll
      for (int e = 0; e < 4; ++e) {
        const int d0 = ks * 16 + lh * 8 + e * 2;
        const float va = Asrc[(size_t)d0 * Nn + xg] * Wmb[d0];
        const float vb = Asrc[(size_t)(d0 + 1) * Nn + xg] * Wmb[d0 + 1];
        sig2 += va * va + vb * vb;
        const uint32_t ha = f2bf(va), hb = f2bf(vb);
        th.u[e] = ha | (hb << 16);
        tl.u[e] = f2bf(va - bf2f(ha)) | (f2bf(vb - bf2f(hb)) << 16);
      }
      xfh[ks] = th.v; xfl[ks] = tl.v;
    }
  }
  sig2 += __shfl_xor(sig2, 32);           // combine the two d-halves (same x)
  const float c3 = 3.0f * sqrtf(sig2);    // fixed per-x shift

  floatx16 acc[4];
#pragma unroll
  for (int dt = 0; dt < 4; ++dt)
#pragma unroll
    for (int r = 0; r < 16; ++r) acc[dt][r] = 0.f;
  float s_run = 0.f;

#pragma unroll 1
  for (int it = 0; it < Nn / 32; ++it) {
    const int y0 = it * 32;

    // ---- streamed B-fragments (hi/lo), direct from global ----
    const uint16_t* bph = BTh + (size_t)(y0 + l31) * 128 + lh * 8;
    const uint16_t* bpl = BTl + (size_t)(y0 + l31) * 128 + lh * 8;
    short8 bh[8], bl[8];
#pragma unroll
    for (int ks = 0; ks < 8; ++ks) bh[ks] = *(const short8*)(bph + ks * 16);
#pragma unroll
    for (int ks = 0; ks < 8; ++ks) bl[ks] = *(const short8*)(bpl + ks * 16);
    F4 bv[4];
#pragma unroll
    for (int gq = 0; gq < 4; ++gq)
      bv[gq].v = *(const float4*)(byp + y0 + 4 * lh + 8 * gq);

    // ---- S^T: 3 independent 8-deep MFMA chains ----
    floatx16 Sa, Sb, S1;
#pragma unroll
    for (int r = 0; r < 16; ++r) { Sa[r] = 0.f; Sb[r] = 0.f; S1[r] = 0.f; }
    __builtin_amdgcn_s_setprio(1);
#pragma unroll
    for (int ks = 0; ks < 8; ++ks) {
      Sa = MFMA(bh[ks], xfh[ks], Sa);
      Sb = MFMA(bh[ks], xfl[ks], Sb);
      S1 = MFMA(bl[ks], xfh[ks], S1);
    }
    __builtin_amdgcn_s_setprio(0);

    // ---- V fragments (permuted-k addressing), issued before exp ----
    short8 vf[4][2];
#pragma unroll
    for (int dt = 0; dt < 4; ++dt)
#pragma unroll
      for (int t = 0; t < 2; ++t) {
        const uint16_t* vp = Vb + (size_t)(dt * 32 + l31) * Nn + y0 + 16 * t + 4 * lh;
        const uint2 lo = *(const uint2*)vp;
        const uint2 hi = *(const uint2*)(vp + 8);
        U8 tv; tv.u[0] = lo.x; tv.u[1] = lo.y; tv.u[2] = hi.x; tv.u[3] = hi.y;
        vf[dt][t] = tv.v;
      }

    // ---- exp with fixed shift; pack P directly into PV B-frags ----
    short8 pf[2];
#pragma unroll
    for (int t = 0; t < 2; ++t) {
      U8 pw;
#pragma unroll
      for (int e = 0; e < 4; ++e) {
        const int r0 = 8 * t + 2 * e, r1 = r0 + 1;
        const float e0 = __expf(Sa[r0] + Sb[r0] + S1[r0] + (bv[r0 >> 2].f[r0 & 3] - c3));
        const float e1 = __expf(Sa[r1] + Sb[r1] + S1[r1] + (bv[r1 >> 2].f[r1 & 3] - c3));
        s_run += e0 + e1;
        pw.u[e] = f2bf(e0) | (f2bf(e1) << 16);
      }
      pf[t] = pw.v;
    }

    // ---- PV: 4 independent acc chains ----
    __builtin_amdgcn_s_setprio(1);
#pragma unroll
    for (int dt = 0; dt < 4; ++dt)
#pragma unroll
      for (int t = 0; t < 2; ++t)
        acc[dt] = MFMA(vf[dt][t], pf[t], acc[dt]);
    __builtin_amdgcn_s_setprio(0);
  }

  // ---- normalize + store ----
  const float s_tot = s_run + __shfl_xor(s_run, 32);
  const float inv = 1.0f / s_tot;
  const int x = x0 + l31;
  if (mode == 0) {
    uint16_t* ou = (uint16_t*)(outb + 2 * DN);        // U2 bf16 -> slot2-lo
#pragma unroll
    for (int dt = 0; dt < 4; ++dt)
#pragma unroll
      for (int r = 0; r < 16; ++r) {
        const int d = dt * 32 + (r & 3) + 8 * (r >> 2) + 4 * lh;
        ou[(size_t)d * Nn + x] = (uint16_t)f2bf(acc[dt][r] * inv);
      }
  } else if (mode == 1) {
    float* oa = outb + 3 * DN;                        // A fp32 -> slot3
#pragma unroll
    for (int dt = 0; dt < 4; ++dt)
#pragma unroll
      for (int r = 0; r < 16; ++r) {
        const int d = dt * 32 + (r & 3) + 8 * (r >> 2) + 4 * lh;
        oa[(size_t)d * Nn + x] = acc[dt][r] * inv;
      }
  } else {
#pragma unroll
    for (int dt = 0; dt < 4; ++dt)
#pragma unroll
      for (int r = 0; r < 16; ++r) {
        const int d = dt * 32 + (r & 3) + 8 * (r >> 2) + 4 * lh;
        float* ob = (dt < 2) ? (outb + (size_t)d * Nn)                      // slot0-lo
                             : (outb + 2 * DN + DN / 2 + (size_t)(d - 64) * Nn);  // slot2-hi
        ob[x] = acc[dt][r] * inv;
      }
  }
}

// ---------------- epilogue: concat + exact-JAX dropout, in place ----------------
// At entry: slot3=A fp32, Bt fp32 @ slot0-lo (d<64) / slot2-hi (d>=64).
// Final: slot0=drop(C), slot1=drop(A), slot2=drop(C*A), slot3=drop(C*Bt).
// Thread owns all 4 slot positions + its A/Bt reads share its flat index: race-free.
__global__ void epilogue_kernel(const float* __restrict__ Cp, float* __restrict__ outp) {
  const int g = blockIdx.x * 256 + threadIdx.x;
  const int b = g >> 18;
  const int rem = g & ((1 << 18) - 1);
  const int dd = rem >> 11;
  const float c = Cp[g];
  const int base = (b << 20) + rem;
  const float a = outp[base + (3 << 18)];                       // A from slot3
  const float bt = outp[base + ((dd >= 64) ? (2 << 18) : 0)];   // Bt split regions
  const float vals[4] = {c, a, c * a, c * bt};
#pragma unroll
  for (int s = 0; s < 4; ++s) {
    const int j = base + (s << 18);
    outp[j] = keep_flag((uint32_t)j) ? vals[s] * INV_KEEP : 0.0f;
  }
}

// ---------------- launch ----------------
extern "C" void kernel_launch(void* const* d_in, const int* in_sizes, int n_in,
                              void* d_out, int out_size, void* d_ws, size_t ws_size,
                              hipStream_t stream) {
  (void)in_sizes; (void)n_in; (void)out_size; (void)ws_size;
  const float* C = (const float*)d_in[0];
  const float* Q = (const float*)d_in[1];
  const float* W = (const float*)d_in[2];
  float* out = (float*)d_out;
  float* ws = (float*)d_ws;

  float* sc = ws;             // [B*N]
  float* sq = ws + Bn * Nn;   // [B*M]

  cvt_kernel<<<(Bn * DN) / (256 * 8), 256, 0, stream>>>(C, Q, out);
  split_kernel<<<dim3(Nn / 64, 2, Bn), 256, 0, stream>>>(C, Q, out);
  scq_kernel<<<dim3(Nn / 256, Bn, 2), 256, 0, stream>>>(C, Q, W, sc, sq);
  bias_adjust_kernel<<<2 * Bn, 256, 0, stream>>>(sc, sq);
  flash_kernel<<<Bn * 64, 64, 0, stream>>>(C, Q, W, out, sc, sq, 0);       // U2
  flash_kernel<<<Bn * 128, 64, 0, stream>>>(C, Q, W, out, sc, sq, 1);      // A + Bt
  epilogue_kernel<<<(Bn * DN) / 256, 256, 0, stream>>>(C, out);
}

// Round 4
// 575.229 us; speedup vs baseline: 2.2453x; 2.2453x over previous
//
#include <hip/hip_runtime.h>
#include <cstdint>
#include <cstddef>

// ---------------- problem constants ----------------
constexpr int Bn = 24;
constexpr int Dd = 128;
constexpr int Nn = 2048;
constexpr int DN = Dd * Nn;        // 262144 elements per (b, slot)
constexpr int NIT = Nn / 64;       // 32 streamed tiles
constexpr float INV_KEEP = 1.0f / 0.9f;

// ---------------- vector types ----------------
typedef __attribute__((ext_vector_type(8))) short short8;     // 8 bf16 in 4 VGPRs
typedef __attribute__((ext_vector_type(16))) float floatx16;  // MFMA 32x32 acc

union U8 { uint32_t u[4]; short8 v; uint4 q; };

__device__ __forceinline__ uint32_t f2bf(float f) {
  uint32_t u = __builtin_bit_cast(uint32_t, f);
  return (u + 0x7fffu + ((u >> 16) & 1u)) >> 16;   // RNE
}
__device__ __forceinline__ float bf2f(uint32_t h) {
  return __builtin_bit_cast(float, h << 16);
}

__device__ __forceinline__ floatx16 MFMA(short8 a, short8 b, floatx16 c) {
  return __builtin_amdgcn_mfma_f32_32x32x16_bf16(a, b, c, 0, 0, 0);
}

// async global->LDS, 16B per lane. LDS dest = wave-uniform base + lane*16.
__device__ __forceinline__ void gload_lds16(const void* g, void* l) {
  __builtin_amdgcn_global_load_lds(
      (const __attribute__((address_space(1))) void*)g,
      (__attribute__((address_space(3))) void*)l, 16, 0, 0);
}

// LDS-only barrier: drain lgkm but NOT vmcnt (async staging loads stay in
// flight). lgkmcnt(0) before s_barrier closes LDS WAR windows.
__device__ __forceinline__ void barrier_lgkm() {
  asm volatile("s_waitcnt lgkmcnt(0)" ::: "memory");
  __builtin_amdgcn_s_barrier();
}

// ---------------- threefry2x32, key = jax.random.key(42) => (0, 42) ----------------
__device__ __forceinline__ uint32_t rotl32(uint32_t x, int r) {
  return (x << r) | (x >> (32 - r));
}
__device__ __forceinline__ void tf2x32(uint32_t& x0, uint32_t& x1) {
  const uint32_t k0 = 0u, k1 = 42u, k2 = 0x1BD11BDAu ^ 0u ^ 42u;
  x0 += k0; x1 += k1;
#define TFR(r) { x0 += x1; x1 = rotl32(x1, (r)); x1 ^= x0; }
  TFR(13) TFR(15) TFR(26) TFR(6)   x0 += k1; x1 += k2 + 1u;
  TFR(17) TFR(29) TFR(16) TFR(24)  x0 += k2; x1 += k0 + 2u;
  TFR(13) TFR(15) TFR(26) TFR(6)   x0 += k0; x1 += k1 + 3u;
  TFR(17) TFR(29) TFR(16) TFR(24)  x0 += k1; x1 += k2 + 4u;
  TFR(13) TFR(15) TFR(26) TFR(6)   x0 += k2; x1 += k0 + 5u;
#undef TFR
}
__device__ __forceinline__ bool keep_flag(uint32_t j) {
  uint32_t x0 = 0u, x1 = j;       // partitionable threefry (verified passing R2-R4)
  tf2x32(x0, x1);
  return ((x0 ^ x1) >> 9) < 7549747u;
}

// ---------------- P0: sc[b,n] = sum_d Wc[b,d] C[b,d,n]; sq = Wq . Q ----------------
__global__ void scq_kernel(const float* __restrict__ Cp, const float* __restrict__ Qp,
                           const float* __restrict__ Wp,
                           float* __restrict__ sc, float* __restrict__ sq) {
  const int z = blockIdx.z;
  const int b = blockIdx.y;
  const int n = blockIdx.x * 256 + threadIdx.x;
  const float* X = z ? Qp : Cp;
  const float* Wb = Wp + b * 384 + (z ? 0 : 128);
  const float* Xb = X + (size_t)b * DN + n;
  float acc = 0.f;
#pragma unroll 8
  for (int d = 0; d < Dd; ++d) acc = fmaf(Wb[d], Xb[(size_t)d * Nn], acc);
  (z ? sq : sc)[b * Nn + n] = acc;
}

// ---------------- cvt: C,Q fp32 [d][n] -> bf16 [d][n] into slot0 (lo=C, hi=Q) ----
__global__ __launch_bounds__(256) void cvt_kernel(const float* __restrict__ Cp,
                                                  const float* __restrict__ Qp,
                                                  float* __restrict__ outp) {
  const size_t i = ((size_t)blockIdx.x * 256 + threadIdx.x) * 8;   // over Bn*DN
  const int b = (int)(i >> 18);
  const int rem = (int)(i & (DN - 1));
  uint16_t* d0 = (uint16_t*)(outp + (size_t)b * 4 * DN);
  {
    const float4 a = *(const float4*)(Cp + i);
    const float4 c = *(const float4*)(Cp + i + 4);
    U8 t;
    t.u[0] = f2bf(a.x) | (f2bf(a.y) << 16);
    t.u[1] = f2bf(a.z) | (f2bf(a.w) << 16);
    t.u[2] = f2bf(c.x) | (f2bf(c.y) << 16);
    t.u[3] = f2bf(c.z) | (f2bf(c.w) << 16);
    *(uint4*)(d0 + rem) = t.q;
  }
  {
    const float4 a = *(const float4*)(Qp + i);
    const float4 c = *(const float4*)(Qp + i + 4);
    U8 t;
    t.u[0] = f2bf(a.x) | (f2bf(a.y) << 16);
    t.u[1] = f2bf(a.z) | (f2bf(a.w) << 16);
    t.u[2] = f2bf(c.x) | (f2bf(c.y) << 16);
    t.u[3] = f2bf(c.z) | (f2bf(c.w) << 16);
    *(uint4*)(d0 + DN + rem) = t.q;
  }
}

// ---------------- split+transpose: X[b][d][n] fp32 -> hi/lo bf16 [b][n][d] -------
// Q -> slot1 ; C -> slot3. (hi first DN ushorts, lo next DN)
__global__ __launch_bounds__(256) void split_kernel(const float* __restrict__ Cp,
                                                    const float* __restrict__ Qp,
                                                    float* __restrict__ outp) {
  __shared__ float T[64 * 129];
  const int tid = threadIdx.x;
  const int nt = blockIdx.x, src = blockIdx.y, b = blockIdx.z;
  const float* X = (src ? Qp : Cp) + (size_t)b * DN;
  float* outb = outp + (size_t)b * 4 * DN;
  uint16_t* dsth = (uint16_t*)(outb + (size_t)(src ? 1 : 3) * DN);
  uint16_t* dstl = dsth + DN;
  const int n = nt * 64 + (tid & 63);
  const int dg0 = (tid >> 6) * 32;
#pragma unroll
  for (int r = 0; r < 32; ++r)
    T[(tid & 63) * 129 + dg0 + r] = X[(size_t)(dg0 + r) * Nn + n];
  __syncthreads();
#pragma unroll
  for (int r = 0; r < 4; ++r) {
    const int item = tid + 256 * r;
    const int row = item >> 4;
    const int ch = item & 15;
    const float* tp = T + row * 129 + ch * 8;
    U8 H, L;
#pragma unroll
    for (int e = 0; e < 4; ++e) {
      const float va = tp[2 * e], vb = tp[2 * e + 1];
      const uint32_t ha = f2bf(va), hb = f2bf(vb);
      H.u[e] = ha | (hb << 16);
      L.u[e] = f2bf(va - bf2f(ha)) | (f2bf(vb - bf2f(hb)) << 16);
    }
    const size_t o = (size_t)(nt * 64 + row) * 128 + ch * 8;
    *(uint4*)(dsth + o) = H.q;
    *(uint4*)(dstl + o) = L.q;
  }
}

// ---------------- fused flash pass (R0 structure, spill-free) --------------------
// DUAL=false (P2): x=m, stream y=n. S2 weights; U2 = C . S2 -> slot2-lo (bf16).
// DUAL=true  (P34): x=n, stream y=m. S1 weights; A = Q . S1 -> slot3 (fp32);
//                   Bt = U2 . S1 -> slot0-lo (d<64) / slot2-hi (d>=64) (fp32).
// B-tile staged via global_load_lds (no VGPR round-trip), double-buffered;
// staging for t+1 issued right after (S) -> one full iteration of latency cover.
// LDS layout keeps the XOR swizzle via pre-swizzled per-lane GLOBAL source
// (XOR is an involution; dest is linear as HW requires).
// Register budget: xf 64 + acc 64 + S 48 + vf 32 + misc ~ 230 < 256
// (__launch_bounds__(256,2)) -> no scratch spills (R0-R3's hidden bottleneck).
template<bool DUAL>
__global__ __launch_bounds__(256, 2) void pass_kernel(
    const float* __restrict__ Cp, const float* __restrict__ Qp,
    const float* __restrict__ Wp, float* __restrict__ outp,
    const float* __restrict__ scp, const float* __restrict__ sqp) {
  __shared__ uint16_t Bs[2][2][64 * 128];  // [buf][hi/lo][y][d] swizzled, 64 KiB
  __shared__ uint16_t EsS[64 * 64];        // weights bf16 (swizzled), 8 KiB
  __shared__ float pmax[128];              // [2][64] per-yh partial max
  __shared__ float al_l[64];               // alpha per x
  __shared__ float spart[128];             // [2][64] final sum partials

  const int tid = threadIdx.x;
  const int lane = tid & 63;
  const int w = tid >> 6;
  const int xh = w >> 1, yh = w & 1;
  const int lh = lane >> 5, l31 = lane & 31;

  // XCD-bijective mapping: 768 = 8 XCD x (3 b x 32 x-tiles)
  const int bid = blockIdx.x;
  const int jj = bid >> 3;
  const int b = (bid & 7) * 3 + (jj >> 5);
  const int x0 = (jj & 31) * 64;

  const float* Cb = Cp + (size_t)b * DN;
  const float* Qb = Qp + (size_t)b * DN;
  float* outb = outp + (size_t)b * 4 * DN;
  const float* Wmb = Wp + b * 384 + 256;

  const float* Asrc = DUAL ? Cb : Qb;        // x-side source (fp32, hi/lo split here)
  const uint16_t* V1 = (const uint16_t*)outb + (DUAL ? DN : 0);        // Qbf16 / Cbf16
  const uint16_t* V2 = DUAL ? (const uint16_t*)(outb + 2 * DN) : nullptr;  // U2bf16
  const uint16_t* BTh = (const uint16_t*)(outb + (size_t)(DUAL ? 1 : 3) * DN);
  const uint16_t* BTl = BTh + DN;
  const float* byp = (DUAL ? sqp : scp) + b * Nn;

  // ---- async staging of one 64-row hi/lo tile into Bs[bn] ----
  // slot s = y*16 + c (16-byte chunks, 16 per row). Lane covers s = w*256+j*64+lane.
  // LDS dest linear in s (wave-uniform base + lane*16); global source chunk is
  // c ^ (y&15) so the READ-side XOR swizzle sees correct data.
  auto stage = [&](int bn, int y0n) {
#pragma unroll
    for (int j = 0; j < 4; ++j) {
      const int s = w * 256 + j * 64 + lane;
      const int y = s >> 4;
      const int cs = ((s & 15) ^ (y & 15)) * 8;
      const size_t gof = (size_t)(y0n + y) * 128 + cs;
      const int lof = (w * 256 + j * 64) * 8;   // wave-uniform
      gload_lds16(BTh + gof, &Bs[bn][0][lof]);
      gload_lds16(BTl + gof, &Bs[bn][1][lof]);
    }
  };

  // ---- x-side fragments (wm * Asrc), hi/lo split, resident all 32 iters ----
  short8 xfh[8], xfl[8];
  {
    const int xg = x0 + xh * 32 + l31;
#pragma unroll
    for (int ks = 0; ks < 8; ++ks) {
      U8 th, tl;
#pragma unroll
      for (int e = 0; e < 4; ++e) {
        const int d0 = ks * 16 + lh * 8 + e * 2;
        const float va = Asrc[(size_t)d0 * Nn + xg] * Wmb[d0];
        const float vb = Asrc[(size_t)(d0 + 1) * Nn + xg] * Wmb[d0 + 1];
        const uint32_t ha = f2bf(va), hb = f2bf(vb);
        th.u[e] = ha | (hb << 16);
        tl.u[e] = f2bf(va - bf2f(ha)) | (f2bf(vb - bf2f(hb)) << 16);
      }
      xfh[ks] = th.v; xfl[ks] = tl.v;
    }
  }

  float m_run = -__builtin_inff();
  float s_run = 0.f;

  floatx16 aA0, aA1, aB0, aB1;
#pragma unroll
  for (int r = 0; r < 16; ++r) { aA0[r] = 0.f; aA1[r] = 0.f; }
  if constexpr (DUAL) {
#pragma unroll
    for (int r = 0; r < 16; ++r) { aB0[r] = 0.f; aB1[r] = 0.f; }
  }

  const int yrow = yh * 32 + l31;
  const int xl = xh * 32 + l31;
  const int dloc = w * 32 + l31;
  const int ybias = yh * 32 + 4 * lh;

  // prologue: stage tile 0
  stage(0, 0);

#pragma unroll 1
  for (int it = 0; it < NIT; ++it) {
    const int y0i = it * 64;
    const int cur = it & 1;

    // (S): own staging loads complete (vmcnt drain is ~free: issued a full
    // iteration ago) + all waves' LDS writes visible.
    __syncthreads();

    // issue async staging for next tile into the other buffer (its readers
    // finished two barriers ago); stays in flight through this whole iter.
    if (it + 1 < NIT) stage(cur ^ 1, y0i + 64);

    // bias for this tile (global, L1-broadcast; per-x bias cancels in softmax)
    float4 bv[4];
#pragma unroll
    for (int gq = 0; gq < 4; ++gq)
      bv[gq] = *(const float4*)(byp + y0i + ybias + 8 * gq);

    // ---- S^T via split-bf16 MFMA: 3 independent 8-deep chains ----
    const uint16_t* brH = &Bs[cur][0][yrow * 128];
    const uint16_t* brL = &Bs[cur][1][yrow * 128];
    floatx16 Sa, Sb, Sc;
#pragma unroll
    for (int r = 0; r < 16; ++r) { Sa[r] = 0.f; Sb[r] = 0.f; Sc[r] = 0.f; }
#pragma unroll
    for (int ks = 0; ks < 8; ++ks) {
      const int ch = ((2 * ks + lh) ^ (yrow & 15)) * 8;
      const short8 bh = *(const short8*)(brH + ch);
      const short8 bl = *(const short8*)(brL + ch);
      Sa = MFMA(bh, xfh[ks], Sa);
      Sb = MFMA(bl, xfh[ks], Sb);
      Sc = MFMA(bh, xfl[ks], Sc);
    }

    // logits
    float Sv[16];
#pragma unroll
    for (int gq = 0; gq < 4; ++gq) {
      Sv[4 * gq + 0] = Sa[4 * gq + 0] + Sb[4 * gq + 0] + Sc[4 * gq + 0] + bv[gq].x;
      Sv[4 * gq + 1] = Sa[4 * gq + 1] + Sb[4 * gq + 1] + Sc[4 * gq + 1] + bv[gq].y;
      Sv[4 * gq + 2] = Sa[4 * gq + 2] + Sb[4 * gq + 2] + Sc[4 * gq + 2] + bv[gq].z;
      Sv[4 * gq + 3] = Sa[4 * gq + 3] + Sb[4 * gq + 3] + Sc[4 * gq + 3] + bv[gq].w;
    }

    // ---- per-x max over this wave's 32 y ----
    float mp = Sv[0];
#pragma unroll
    for (int r = 1; r < 16; ++r) mp = fmaxf(mp, Sv[r]);
    mp = fmaxf(mp, __shfl_xor(mp, 32));
    if (lh == 0) pmax[yh * 64 + xl] = mp;
    barrier_lgkm();  // (1) pmax visible; staging loads stay in flight

    const float pmx = fmaxf(pmax[xl], pmax[64 + xl]);
    const float mn = fmaxf(m_run, pmx);
    const float alpha = __expf(m_run - mn);   // -inf first iter -> 0
    m_run = mn;
    s_run *= alpha;
    if (yh == 0 && lh == 0) al_l[xl] = alpha;

    // ---- issue V fragment loads (bf16, direct); covered by exp below ----
    short8 vf1[4], vf2[4];
    {
      const uint16_t* v1p = V1 + (size_t)dloc * Nn + y0i + lh * 8;
#pragma unroll
      for (int ks = 0; ks < 4; ++ks)
        vf1[ks] = *(const short8*)(v1p + ks * 16);
      if constexpr (DUAL) {
        const uint16_t* v2p = V2 + (size_t)dloc * Nn + y0i + lh * 8;
#pragma unroll
        for (int ks = 0; ks < 4; ++ks)
          vf2[ks] = *(const short8*)(v2p + ks * 16);
      }
    }

    // ---- exp, Es write (b64, swizzled), in-reg sum ----
    float sp = 0.f;
#pragma unroll
    for (int gq = 0; gq < 4; ++gq) {
      const float e0 = __expf(Sv[4 * gq + 0] - m_run);
      const float e1 = __expf(Sv[4 * gq + 1] - m_run);
      const float e2 = __expf(Sv[4 * gq + 2] - m_run);
      const float e3 = __expf(Sv[4 * gq + 3] - m_run);
      sp += (e0 + e1) + (e2 + e3);
      uint2 pk;
      pk.x = f2bf(e0) | (f2bf(e1) << 16);
      pk.y = f2bf(e2) | (f2bf(e3) << 16);
      const int c = 4 * yh + gq;
      *(uint2*)(EsS + xl * 64 + ((c ^ (xl & 7)) * 8 + 4 * lh)) = pk;
    }
    sp += __shfl_xor(sp, 32);
    s_run += sp;   // per-yh partial; alpha-chain shared so partials sum at end
    barrier_lgkm();  // (2) Es + al_l visible; staging + V loads in flight

    // ---- consumers: rescale + V . Es ----
    const float a0 = al_l[l31], a1 = al_l[32 + l31];
#pragma unroll
    for (int r = 0; r < 16; ++r) { aA0[r] *= a0; aA1[r] *= a1; }
    if constexpr (DUAL) {
#pragma unroll
      for (int r = 0; r < 16; ++r) { aB0[r] *= a0; aB1[r] *= a1; }
    }
#pragma unroll
    for (int ks = 0; ks < 4; ++ks) {
      const int sw = ((2 * ks + lh) ^ (l31 & 7)) * 8;
      const short8 e0 = *(const short8*)(EsS + l31 * 64 + sw);
      const short8 e1 = *(const short8*)(EsS + (32 + l31) * 64 + sw);
      aA0 = MFMA(vf1[ks], e0, aA0);
      aA1 = MFMA(vf1[ks], e1, aA1);
      if constexpr (DUAL) {
        aB0 = MFMA(vf2[ks], e0, aB0);
        aB1 = MFMA(vf2[ks], e1, aB1);
      }
    }
  }

  // ---- combine sum partials across yh, normalize, store ----
  if (lh == 0) spart[yh * 64 + xl] = s_run;
  __syncthreads();
  const float inv0 = 1.0f / (spart[l31] + spart[64 + l31]);
  const float inv1 = 1.0f / (spart[32 + l31] + spart[96 + l31]);
#pragma unroll
  for (int r = 0; r < 16; ++r) {
    const int d = w * 32 + (r & 3) + 8 * (r >> 2) + 4 * lh;
    if constexpr (DUAL) {
      // A -> slot3 fp32
      float* oa = outb + 3 * DN + (size_t)d * Nn + x0;
      oa[l31] = aA0[r] * inv0;
      oa[32 + l31] = aA1[r] * inv1;
      // Bt -> slot0-lo (d<64) / slot2-hi (d>=64) fp32 (wave-uniform branch)
      float* ob = (d < 64) ? (outb + (size_t)d * Nn + x0)
                           : (outb + 2 * DN + DN / 2 + (size_t)(d - 64) * Nn + x0);
      ob[l31] = aB0[r] * inv0;
      ob[32 + l31] = aB1[r] * inv1;
    } else {
      // U2 -> slot2-lo bf16 [d][n]
      uint16_t* ou = (uint16_t*)(outb + 2 * DN) + (size_t)d * Nn + x0;
      ou[l31] = (uint16_t)f2bf(aA0[r] * inv0);
      ou[32 + l31] = (uint16_t)f2bf(aA1[r] * inv1);
    }
  }
}

// ---------------- epilogue: concat + exact-JAX dropout, in place ----------------
// At entry: slot3=A fp32, Bt fp32 @ slot0-lo (d<64) / slot2-hi (d>=64).
// Final: slot0=drop(C), slot1=drop(A), slot2=drop(C*A), slot3=drop(C*Bt).
// Thread owns all 4 slot positions + its A/Bt reads share its flat index: race-free.
__global__ void epilogue_kernel(const float* __restrict__ Cp, float* __restrict__ outp) {
  const int g = blockIdx.x * 256 + threadIdx.x;
  const int b = g >> 18;
  const int rem = g & ((1 << 18) - 1);
  const int dd = rem >> 11;
  const float c = Cp[g];
  const int base = (b << 20) + rem;
  const float a = outp[base + (3 << 18)];                       // A from slot3
  const float bt = outp[base + ((dd >= 64) ? (2 << 18) : 0)];   // Bt split regions
  const float vals[4] = {c, a, c * a, c * bt};
#pragma unroll
  for (int s = 0; s < 4; ++s) {
    const int j = base + (s << 18);
    outp[j] = keep_flag((uint32_t)j) ? vals[s] * INV_KEEP : 0.0f;
  }
}

// ---------------- launch ----------------
extern "C" void kernel_launch(void* const* d_in, const int* in_sizes, int n_in,
                              void* d_out, int out_size, void* d_ws, size_t ws_size,
                              hipStream_t stream) {
  (void)in_sizes; (void)n_in; (void)out_size; (void)ws_size;
  const float* C = (const float*)d_in[0];
  const float* Q = (const float*)d_in[1];
  const float* W = (const float*)d_in[2];
  float* out = (float*)d_out;
  float* ws = (float*)d_ws;

  float* sc = ws;             // [B*N]
  float* sq = ws + Bn * Nn;   // [B*M]

  cvt_kernel<<<(Bn * DN) / (256 * 8), 256, 0, stream>>>(C, Q, out);
  split_kernel<<<dim3(Nn / 64, 2, Bn), 256, 0, stream>>>(C, Q, out);
  scq_kernel<<<dim3(Nn / 256, Bn, 2), 256, 0, stream>>>(C, Q, W, sc, sq);
  pass_kernel<false><<<dim3(Nn / 64 * Bn), 256, 0, stream>>>(C, Q, W, out, sc, sq);
  pass_kernel<true><<<dim3(Nn / 64 * Bn), 256, 0, stream>>>(C, Q, W, out, sc, sq);
  epilogue_kernel<<<(Bn * DN) / 256, 256, 0, stream>>>(C, out);
}